// Round 4
// baseline (122.010 us; speedup 1.0000x reference)
//
#include <hip/hip_runtime.h>
#include <hip/hip_cooperative_groups.h>
#include <math.h>

namespace cg = cooperative_groups;

// PointPillarFeatureNet, single cooperative kernel.
//  phase1: stage 64 pillars/block to LDS; per-pillar raw moments (quad of
//          lanes) -> rank-1 corrections -> 54 augmented-feature moment sums
//          reduced block-wide -> ws[b*64+e] (no atomics, no memset).
//  grid.sync()
//  phase2: every block reduces the gridDim partials; BN mean/var derived in
//          closed form (54 sums), folded into pre-scaled weights.
//  phase3: per-pillar max over valid slots (4-MAC dot per slot, LDS
//          broadcast reads) + implicit masked-slot value t, ReLU, store.

#define NSLOT 32
#define NCH 64
#define PPB 64        // pillars per block (= quads per block)
#define PSTRIDE 132   // padded dword stride per pillar in LDS (16B-aligned)

static constexpr float kVX = 0.16f, kVY = 0.16f;
static constexpr float kXOff = 0.08f;            // VX/2 + 0.0
static constexpr float kYOff = 0.08f - 39.68f;   // VY/2 - 39.68
static constexpr float kEps = 1e-3f;
static constexpr float kNegInf = -3.402823466e38f;

__device__ __forceinline__ float dot4(const float4 u, float V0, float V1,
                                      float V2, float V3, float c0) {
    return fmaf(u.x, V0, fmaf(u.y, V1, fmaf(u.z, V2, fmaf(u.w, V3, c0))));
}

__global__ __launch_bounds__(256, 2) void k_fused(
    const float* __restrict__ in, const int* __restrict__ npts,
    const int* __restrict__ coords, const float* __restrict__ W,
    const float* __restrict__ gamma, const float* __restrict__ beta,
    float* __restrict__ ws, float* __restrict__ out, int P) {
    __shared__ float sl[PPB * PSTRIDE];   // pillar data, padded
    __shared__ float smeta[PPB * 8];      // mx,my,mz,npf,cx,cy per pillar
    __shared__ float sred[16 * 57];       // cross-quad / cross-wave scratch
    __shared__ float ssum[64];            // final 54 sums

    const int tid = threadIdx.x;
    const int lane = tid & 63;
    const int wv = tid >> 6;
    const int b = blockIdx.x;
    const int p0 = b * PPB;
    const int rem = min(PPB, P - p0);

    // ---------- phase 1a: stage pillars + per-pillar meta ----------
    {
        const float4* g4 = reinterpret_cast<const float4*>(in) + (size_t)p0 * 32;
        const int nf4 = rem * 32;
        for (int f = tid; f < nf4; f += 256) {
            const float4 v = g4[f];
            const int p = f >> 5, r = f & 31;
            *reinterpret_cast<float4*>(&sl[p * PSTRIDE + r * 4]) = v;
        }
        if (tid < rem) {
            int np = npts[p0 + tid];
            np = np < 1 ? 1 : (np > NSLOT ? NSLOT : np);
            const int4 cd = reinterpret_cast<const int4*>(coords)[p0 + tid];
            smeta[tid * 8 + 3] = (float)np;
            smeta[tid * 8 + 4] = (float)cd.w * kVX + kXOff;
            smeta[tid * 8 + 5] = (float)cd.z * kVY + kYOff;
        }
    }
    __syncthreads();

    // ---------- phase 1b: per-pillar moments (quad of lanes) ----------
    float acc[54];
#pragma unroll
    for (int i = 0; i < 54; ++i) acc[i] = 0.f;
    {
        const int q = tid >> 2;   // pillar within block
        const int sub = tid & 3;
        float T0 = 0.f, T1 = 0.f, T2 = 0.f;
        float S0 = 0.f, S1 = 0.f, S2 = 0.f, S3 = 0.f;
        float Q[10];
#pragma unroll
        for (int i = 0; i < 10; ++i) Q[i] = 0.f;
        float npf = 1.f, cx = 0.f, cy = 0.f;

        if (q < rem) {
            npf = smeta[q * 8 + 3];
            cx = smeta[q * 8 + 4];
            cy = smeta[q * 8 + 5];
            const int np = (int)npf;
            const float* base = &sl[q * PSTRIDE];
#pragma unroll
            for (int k = 0; k < 8; ++k) {
                const float4 u = *reinterpret_cast<const float4*>(base + (sub + 4 * k) * 4);
                const int slot = sub + 4 * k;
                T0 += u.x; T1 += u.y; T2 += u.z;
                const bool m = slot < np;
                const float ax = m ? u.x : 0.f, ay = m ? u.y : 0.f;
                const float az = m ? u.z : 0.f, aw = m ? u.w : 0.f;
                S0 += ax; S1 += ay; S2 += az; S3 += aw;
                Q[0] += ax * u.x; Q[1] += ax * u.y; Q[2] += ax * u.z; Q[3] += ax * u.w;
                Q[4] += ay * u.y; Q[5] += ay * u.z; Q[6] += ay * u.w;
                Q[7] += az * u.z; Q[8] += az * u.w;
                Q[9] += aw * u.w;
            }
        }

#define QUADR(v) { v += __shfl_xor(v, 1); v += __shfl_xor(v, 2); }
        QUADR(T0) QUADR(T1) QUADR(T2)
        QUADR(S0) QUADR(S1) QUADR(S2) QUADR(S3)
#pragma unroll
        for (int i = 0; i < 10; ++i) QUADR(Q[i])
#undef QUADR

        if (q < rem && sub == 0) {
            const float inv = 1.0f / npf;
            const float mx = T0 * inv, my = T1 * inv, mz = T2 * inv;
            smeta[q * 8 + 0] = mx;
            smeta[q * 8 + 1] = my;
            smeta[q * 8 + 2] = mz;
            const float AS[9] = {S0, S1, S2, S3, S0, S1, S2, S0, S1};
            const float b9[9] = {0.f, 0.f, 0.f, 0.f, -mx, -my, -mz, -cx, -cy};
            const int r9[9] = {0, 1, 2, 3, 0, 1, 2, 0, 1};
            float Qm[4][4];
            Qm[0][0] = Q[0]; Qm[0][1] = Q[1]; Qm[0][2] = Q[2]; Qm[0][3] = Q[3];
            Qm[1][0] = Q[1]; Qm[1][1] = Q[4]; Qm[1][2] = Q[5]; Qm[1][3] = Q[6];
            Qm[2][0] = Q[2]; Qm[2][1] = Q[5]; Qm[2][2] = Q[7]; Qm[2][3] = Q[8];
            Qm[3][0] = Q[3]; Qm[3][1] = Q[6]; Qm[3][2] = Q[8]; Qm[3][3] = Q[9];
#pragma unroll
            for (int i = 0; i < 9; ++i) acc[i] = AS[i] + npf * b9[i];
            int k = 9;
#pragma unroll
            for (int i = 0; i < 9; ++i)
#pragma unroll
                for (int j = i; j < 9; ++j) {
                    acc[k] = Qm[r9[i]][r9[j]] + AS[i] * b9[j] + b9[i] * AS[j]
                             + npf * b9[i] * b9[j];
                    ++k;
                }
        }

        // cross-quad reduce: 4 quads -> lanes = 0 (mod 16)
#pragma unroll
        for (int i = 0; i < 54; ++i) {
            acc[i] += __shfl_xor(acc[i], 4);
            acc[i] += __shfl_xor(acc[i], 8);
        }
        if ((lane & 15) == 0) {
            const int g = wv * 4 + (lane >> 4);
#pragma unroll
            for (int e = 0; e < 54; ++e) sred[g * 57 + e] = acc[e];
        }
    }
    __syncthreads();

    // block partial -> global (no atomics)
    if (tid < 54) {
        float v = 0.f;
#pragma unroll
        for (int g = 0; g < 16; ++g) v += sred[g * 57 + tid];
        ws[(size_t)b * 64 + tid] = v;
    }
    __threadfence();
    cg::this_grid().sync();
    __threadfence();

    // ---------- phase 2: reduce partials, BN fold ----------
    {
        const int NB = gridDim.x;
        float v = 0.f;
        if (lane < 54) {
#pragma unroll 4
            for (int i = wv; i < NB; i += 4) v += ws[(size_t)i * 64 + lane];
            sred[wv * 57 + lane] = v;
        }
        __syncthreads();
        if (tid < 54)
            ssum[tid] = sred[tid] + sred[57 + tid] + sred[114 + tid] + sred[171 + tid];
        __syncthreads();
    }

    const int d = lane;
    float Wc[9];
#pragma unroll
    for (int c = 0; c < 9; ++c) Wc[c] = W[c * NCH + d];

    const float invPN = 1.0f / ((float)P * (float)NSLOT);
    float mean = 0.f;
#pragma unroll
    for (int c = 0; c < 9; ++c) mean += ssum[c] * Wc[c];
    mean *= invPN;

    float e2 = 0.f;
    {
        int k = 9;
#pragma unroll
        for (int i = 0; i < 9; ++i)
#pragma unroll
            for (int j = i; j < 9; ++j) {
                const float coef = (i == j) ? 1.f : 2.f;
                e2 += coef * ssum[k] * Wc[i] * Wc[j];
                ++k;
            }
    }
    e2 *= invPN;
    const float var = e2 - mean * mean;
    const float s = gamma[d] * rsqrtf(var + kEps);
    const float t = beta[d] - mean * s;

    const float V0 = s * (Wc[0] + Wc[4] + Wc[7]);
    const float V1 = s * (Wc[1] + Wc[5] + Wc[8]);
    const float V2 = s * (Wc[2] + Wc[6]);
    const float V3 = s * Wc[3];
    const float sW4 = s * Wc[4], sW5 = s * Wc[5], sW6 = s * Wc[6];
    const float sW7 = s * Wc[7], sW8 = s * Wc[8];

    // ---------- phase 3: per-pillar max/ReLU from LDS ----------
    for (int q = wv; q < rem; q += 4) {
        const float mx = smeta[q * 8 + 0], my = smeta[q * 8 + 1], mz = smeta[q * 8 + 2];
        const float npf = smeta[q * 8 + 3], cx = smeta[q * 8 + 4], cy = smeta[q * 8 + 5];
        const int np = (int)npf;
        const float c0 = t - (mx * sW4 + my * sW5 + mz * sW6 + cx * sW7 + cy * sW8);
        const float* L = &sl[q * PSTRIDE];
        float y0 = (np < NSLOT) ? t : kNegInf;  // masked slots contribute t
        float y1 = kNegInf, y2 = kNegInf, y3 = kNegInf;
        int n = 0;
        for (; n + 4 <= np; n += 4) {
            const float4 u0 = *reinterpret_cast<const float4*>(L + n * 4);
            const float4 u1 = *reinterpret_cast<const float4*>(L + n * 4 + 4);
            const float4 u2 = *reinterpret_cast<const float4*>(L + n * 4 + 8);
            const float4 u3 = *reinterpret_cast<const float4*>(L + n * 4 + 12);
            y0 = fmaxf(y0, dot4(u0, V0, V1, V2, V3, c0));
            y1 = fmaxf(y1, dot4(u1, V0, V1, V2, V3, c0));
            y2 = fmaxf(y2, dot4(u2, V0, V1, V2, V3, c0));
            y3 = fmaxf(y3, dot4(u3, V0, V1, V2, V3, c0));
        }
        for (; n < np; ++n) {
            const float4 u0 = *reinterpret_cast<const float4*>(L + n * 4);
            y0 = fmaxf(y0, dot4(u0, V0, V1, V2, V3, c0));
        }
        out[(size_t)(p0 + q) * NCH + d] =
            fmaxf(fmaxf(fmaxf(y0, y1), fmaxf(y2, y3)), 0.f);
    }
}

extern "C" void kernel_launch(void* const* d_in, const int* in_sizes, int n_in,
                              void* d_out, int out_size, void* d_ws, size_t ws_size,
                              hipStream_t stream) {
    const float* in = (const float*)d_in[0];
    const int* npts = (const int*)d_in[1];
    const int* coords = (const int*)d_in[2];
    const float* W = (const float*)d_in[3];
    const float* gamma = (const float*)d_in[4];
    const float* beta = (const float*)d_in[5];
    float* out = (float*)d_out;
    float* ws = (float*)d_ws;
    int P = in_sizes[1];  // num_points has P elements

    int nblocks = (P + PPB - 1) / PPB;  // 469 for P=30000; <=512 co-resident
    void* args[] = {(void*)&in, (void*)&npts, (void*)&coords, (void*)&W,
                    (void*)&gamma, (void*)&beta, (void*)&ws, (void*)&out,
                    (void*)&P};
    hipLaunchCooperativeKernel((const void*)k_fused, dim3(nblocks), dim3(256),
                               args, 0, stream);
}

// Round 5
// 38.191 us; speedup vs baseline: 3.1947x; 3.1947x over previous
//
#include <hip/hip_runtime.h>
#include <math.h>

// PointPillarFeatureNet fused, 3 dispatches (coop grid-sync measured 95us+
// overhead on MI355X -> abandoned).
//  k_stats: per-pillar raw moments via quad-of-lanes -> rank-1 corrections ->
//           54 global moment sums (8 replica sets of atomics). Stores
//           per-pillar meta (mean, npf, cx, cy).
//  k_out:   replica-reduce once per block -> BN fold into pre-scaled weights;
//           per-channel lane; slots read as wave-uniform global broadcast
//           loads (no LDS staging); max over valid slots + implicit
//           masked-slot value t; ReLU.
// ws layout (floats): [r*64+e] r<8,e<54 replica sums; [512+8p..] pillar meta.

#define NSLOT 32
#define NCH 64
#define NREP 8
#define META_OFF 512

static constexpr float kVX = 0.16f, kVY = 0.16f;
static constexpr float kXOff = 0.08f;            // VX/2 + 0.0
static constexpr float kYOff = 0.08f - 39.68f;   // VY/2 - 39.68
static constexpr float kEps = 1e-3f;
static constexpr float kNegInf = -3.402823466e38f;

__global__ __launch_bounds__(256) void k_stats(const float* __restrict__ in,
                                               const int* __restrict__ npts,
                                               const int* __restrict__ coords,
                                               float* __restrict__ ws,
                                               float* __restrict__ meta, int P) {
    const int tid = threadIdx.x;
    const int lane = tid & 63;
    const int wv = tid >> 6;
    const int sub = lane & 3;
    const int pi = blockIdx.x * 64 + wv * 16 + (lane >> 2);
    const bool valid = pi < P;

    float T0 = 0.f, T1 = 0.f, T2 = 0.f;
    float S0 = 0.f, S1 = 0.f, S2 = 0.f, S3 = 0.f;
    float Q[10];
#pragma unroll
    for (int i = 0; i < 10; ++i) Q[i] = 0.f;
    float cx = 0.f, cy = 0.f, npf = 1.f;

    if (valid) {
        int np = npts[pi];
        np = np < 1 ? 1 : (np > NSLOT ? NSLOT : np);
        npf = (float)np;
        const int4 cd = *reinterpret_cast<const int4*>(coords + (size_t)pi * 4);
        cx = (float)cd.w * kVX + kXOff;
        cy = (float)cd.z * kVY + kYOff;
        const float* bp = in + (size_t)pi * 128 + sub * 4;
#pragma unroll
        for (int k = 0; k < 8; ++k) {
            const float4 u = *reinterpret_cast<const float4*>(bp + k * 16);
            const int slot = sub + k * 4;
            T0 += u.x; T1 += u.y; T2 += u.z;
            const bool m = slot < np;
            const float ax = m ? u.x : 0.f, ay = m ? u.y : 0.f;
            const float az = m ? u.z : 0.f, aw = m ? u.w : 0.f;
            S0 += ax; S1 += ay; S2 += az; S3 += aw;
            Q[0] += ax * u.x; Q[1] += ax * u.y; Q[2] += ax * u.z; Q[3] += ax * u.w;
            Q[4] += ay * u.y; Q[5] += ay * u.z; Q[6] += ay * u.w;
            Q[7] += az * u.z; Q[8] += az * u.w;
            Q[9] += aw * u.w;
        }
    }

#define QUADR(v) { v += __shfl_xor(v, 1); v += __shfl_xor(v, 2); }
    QUADR(T0) QUADR(T1) QUADR(T2)
    QUADR(S0) QUADR(S1) QUADR(S2) QUADR(S3)
#pragma unroll
    for (int i = 0; i < 10; ++i) QUADR(Q[i])
#undef QUADR

    float acc[54];
#pragma unroll
    for (int i = 0; i < 54; ++i) acc[i] = 0.f;

    if (valid && sub == 0) {
        const float inv = 1.0f / npf;
        const float mx = T0 * inv, my = T1 * inv, mz = T2 * inv;
        if (meta) {
            *reinterpret_cast<float4*>(meta + (size_t)pi * 8) =
                make_float4(mx, my, mz, npf);
            *reinterpret_cast<float4*>(meta + (size_t)pi * 8 + 4) =
                make_float4(cx, cy, 0.f, 0.f);
        }
        const float AS[9] = {S0, S1, S2, S3, S0, S1, S2, S0, S1};
        const float b9[9] = {0.f, 0.f, 0.f, 0.f, -mx, -my, -mz, -cx, -cy};
        const int r9[9] = {0, 1, 2, 3, 0, 1, 2, 0, 1};
        float Qm[4][4];
        Qm[0][0] = Q[0]; Qm[0][1] = Q[1]; Qm[0][2] = Q[2]; Qm[0][3] = Q[3];
        Qm[1][0] = Q[1]; Qm[1][1] = Q[4]; Qm[1][2] = Q[5]; Qm[1][3] = Q[6];
        Qm[2][0] = Q[2]; Qm[2][1] = Q[5]; Qm[2][2] = Q[7]; Qm[2][3] = Q[8];
        Qm[3][0] = Q[3]; Qm[3][1] = Q[6]; Qm[3][2] = Q[8]; Qm[3][3] = Q[9];
#pragma unroll
        for (int i = 0; i < 9; ++i) acc[i] = AS[i] + npf * b9[i];
        int k = 9;
#pragma unroll
        for (int i = 0; i < 9; ++i)
#pragma unroll
            for (int j = i; j < 9; ++j) {
                acc[k] = Qm[r9[i]][r9[j]] + AS[i] * b9[j] + b9[i] * AS[j]
                         + npf * b9[i] * b9[j];
                ++k;
            }
    }

    // reduce across the 16 quad-leader lanes (others hold zeros)
#pragma unroll
    for (int i = 0; i < 54; ++i) {
        acc[i] += __shfl_xor(acc[i], 4);
        acc[i] += __shfl_xor(acc[i], 8);
        acc[i] += __shfl_xor(acc[i], 16);
        acc[i] += __shfl_xor(acc[i], 32);
    }

    __shared__ float red[4][54];
    if (lane == 0) {
#pragma unroll
        for (int i = 0; i < 54; ++i) red[wv][i] = acc[i];
    }
    __syncthreads();
    if (tid < 54) {
        const float v = red[0][tid] + red[1][tid] + red[2][tid] + red[3][tid];
        atomicAdd(&ws[(blockIdx.x & (NREP - 1)) * 64 + tid], v);
    }
}

__device__ __forceinline__ float dot4(const float4 u, float V0, float V1,
                                      float V2, float V3, float c0) {
    return fmaf(u.x, V0, fmaf(u.y, V1, fmaf(u.z, V2, fmaf(u.w, V3, c0))));
}

template <bool MEANS>
__global__ __launch_bounds__(256) void k_out(const float* __restrict__ in,
                                             const int* __restrict__ npts,
                                             const int* __restrict__ coords,
                                             const float* __restrict__ W,
                                             const float* __restrict__ gamma,
                                             const float* __restrict__ beta,
                                             const float* __restrict__ ws,
                                             const float* __restrict__ meta,
                                             float* __restrict__ out, int P) {
    __shared__ float ssum[54];
    const int tid = threadIdx.x;
    const int lane = tid & 63;
    const int wv = tid >> 6;
    const int gwave = blockIdx.x * 4 + wv;
    const int nwave = gridDim.x * 4;
    const int d = lane;

    if (tid < 54) {
        float v = 0.f;
#pragma unroll
        for (int r = 0; r < NREP; ++r) v += ws[r * 64 + tid];
        ssum[tid] = v;
    }
    __syncthreads();

    // ---- BN fold ----
    float Wc[9];
#pragma unroll
    for (int c = 0; c < 9; ++c) Wc[c] = W[c * NCH + d];

    const float invPN = 1.0f / ((float)P * (float)NSLOT);
    float mean = 0.f;
#pragma unroll
    for (int c = 0; c < 9; ++c) mean += ssum[c] * Wc[c];
    mean *= invPN;

    float e2 = 0.f;
    {
        int k = 9;
#pragma unroll
        for (int i = 0; i < 9; ++i)
#pragma unroll
            for (int j = i; j < 9; ++j) {
                const float coef = (i == j) ? 1.f : 2.f;
                e2 += coef * ssum[k] * Wc[i] * Wc[j];
                ++k;
            }
    }
    e2 *= invPN;
    const float var = e2 - mean * mean;
    const float s = gamma[d] * rsqrtf(var + kEps);
    const float t = beta[d] - mean * s;

    const float V0 = s * (Wc[0] + Wc[4] + Wc[7]);
    const float V1 = s * (Wc[1] + Wc[5] + Wc[8]);
    const float V2 = s * (Wc[2] + Wc[6]);
    const float V3 = s * Wc[3];
    const float sW4 = s * Wc[4], sW5 = s * Wc[5], sW6 = s * Wc[6];
    const float sW7 = s * Wc[7], sW8 = s * Wc[8];

    const float4* __restrict__ in4 = reinterpret_cast<const float4*>(in);

    for (int p = gwave; p < P; p += nwave) {
        const int pu = __builtin_amdgcn_readfirstlane(p);  // wave-uniform
        float mx, my, mz, cx, cy;
        int np;
        if (MEANS) {
            const float4 m1 = *reinterpret_cast<const float4*>(meta + (size_t)pu * 8);
            const float4 m2 = *reinterpret_cast<const float4*>(meta + (size_t)pu * 8 + 4);
            mx = m1.x; my = m1.y; mz = m1.z; np = (int)m1.w;
            cx = m2.x; cy = m2.y;
        } else {
            np = npts[pu];
            np = np < 1 ? 1 : (np > NSLOT ? NSLOT : np);
            float T0 = 0.f, T1 = 0.f, T2 = 0.f;
            for (int n = 0; n < NSLOT; ++n) {
                const float4 u = in4[(size_t)pu * 32 + n];
                T0 += u.x; T1 += u.y; T2 += u.z;
            }
            const float inv = 1.0f / (float)np;
            mx = T0 * inv; my = T1 * inv; mz = T2 * inv;
            const int4 cd = *reinterpret_cast<const int4*>(coords + (size_t)pu * 4);
            cx = (float)cd.w * kVX + kXOff;
            cy = (float)cd.z * kVY + kYOff;
        }
        const float c0 = t - (mx * sW4 + my * sW5 + mz * sW6 + cx * sW7 + cy * sW8);
        const float4* __restrict__ U = in4 + (size_t)pu * 32;

        float y0 = (np < NSLOT) ? t : kNegInf;  // masked slots contribute t
        float y1 = kNegInf, y2 = kNegInf, y3 = kNegInf;
        int n = 0;
        for (; n + 4 <= np; n += 4) {
            const float4 u0 = U[n];
            const float4 u1 = U[n + 1];
            const float4 u2 = U[n + 2];
            const float4 u3 = U[n + 3];
            y0 = fmaxf(y0, dot4(u0, V0, V1, V2, V3, c0));
            y1 = fmaxf(y1, dot4(u1, V0, V1, V2, V3, c0));
            y2 = fmaxf(y2, dot4(u2, V0, V1, V2, V3, c0));
            y3 = fmaxf(y3, dot4(u3, V0, V1, V2, V3, c0));
        }
        for (; n < np; ++n) {
            const float4 u0 = U[n];
            y0 = fmaxf(y0, dot4(u0, V0, V1, V2, V3, c0));
        }
        out[(size_t)pu * NCH + d] =
            fmaxf(fmaxf(fmaxf(y0, y1), fmaxf(y2, y3)), 0.f);
    }
}

extern "C" void kernel_launch(void* const* d_in, const int* in_sizes, int n_in,
                              void* d_out, int out_size, void* d_ws, size_t ws_size,
                              hipStream_t stream) {
    const float* in = (const float*)d_in[0];
    const int* npts = (const int*)d_in[1];
    const int* coords = (const int*)d_in[2];
    const float* W = (const float*)d_in[3];
    const float* gamma = (const float*)d_in[4];
    const float* beta = (const float*)d_in[5];
    float* out = (float*)d_out;
    float* ws = (float*)d_ws;
    const int P = in_sizes[1];  // num_points has P elements

    const size_t need = (META_OFF + 8 * (size_t)P) * sizeof(float);
    const bool means = ws_size >= need;
    float* meta = means ? (ws + META_OFF) : nullptr;

    hipMemsetAsync(ws, 0, META_OFF * sizeof(float), stream);
    const int sblocks = (P + 63) / 64;  // 64 pillars per block (4 waves x 16)
    k_stats<<<sblocks, 256, 0, stream>>>(in, npts, coords, ws, meta, P);
    if (means) {
        k_out<true><<<1024, 256, 0, stream>>>(in, npts, coords, W, gamma, beta, ws,
                                              meta, out, P);
    } else {
        k_out<false><<<1024, 256, 0, stream>>>(in, npts, coords, W, gamma, beta, ws,
                                               meta, out, P);
    }
}